// Round 1
// baseline (480.246 us; speedup 1.0000x reference)
//
#include <hip/hip_runtime.h>

typedef float f32x4 __attribute__((ext_vector_type(4)));
typedef __bf16 bf16x8 __attribute__((ext_vector_type(8)));
typedef unsigned short u16x4 __attribute__((ext_vector_type(4)));
typedef unsigned int u32x4 __attribute__((ext_vector_type(4)));

// B=65536, IN=1260 (pad K->1280 = 20 chunks of 64), H=40
// packed gates: [i(0..39), g(40..79), o(80..119)], pad to 128 cols. f-gate unused (c0=0).

__device__ __forceinline__ unsigned short f2bf(float f) {
  unsigned int u = __builtin_bit_cast(unsigned int, f);
  u = (u + 0x7FFFu + ((u >> 16) & 1u)) >> 16;   // RNE
  return (unsigned short)u;
}
__device__ __forceinline__ float sigm(float v) { return 1.0f / (1.0f + __expf(-v)); }
__device__ __forceinline__ float tanh_(float v) { return 1.0f - 2.0f / (__expf(2.0f * v) + 1.0f); }

__device__ __forceinline__ int srow_of(int col) {
  return col + (col < 40 ? 0 : (col < 80 ? 40 : 80));   // packed col -> original gate row
}

// ---------------- prep: pack weights to bf16 chunk images (swizzled), fuse biases ----------------
__global__ __launch_bounds__(256) void prep_kernel(
    const float* __restrict__ W_ih0, const float* __restrict__ b_ih0, const float* __restrict__ b_hh0,
    const float* __restrict__ W_ih1, const float* __restrict__ b_ih1, const float* __restrict__ b_hh1,
    const float* __restrict__ W_ih2, const float* __restrict__ b_ih2, const float* __restrict__ b_hh2,
    unsigned short* __restrict__ W0bf, unsigned short* __restrict__ W1bf,
    unsigned short* __restrict__ W2bf, float* __restrict__ bias)
{
  int idx = blockIdx.x * 256 + threadIdx.x;   // 0..163839
  {
    int c = idx >> 13, rem = idx & 8191;
    int col = rem >> 6, kk = rem & 63;
    int k = (c << 6) + kk;
    unsigned short v = 0;
    if (col < 120 && k < 1260) v = f2bf(W_ih0[srow_of(col) * 1260 + k]);
    W0bf[(c << 13) + (col << 6) + (kk ^ ((col & 7) << 3))] = v;
  }
  if (idx < 8192) {
    int col = idx >> 6, kk = idx & 63;
    unsigned short v1 = 0, v2 = 0;
    if (col < 120 && kk < 40) {
      int sr = srow_of(col);
      v1 = f2bf(W_ih1[sr * 40 + kk]);
      v2 = f2bf(W_ih2[sr * 40 + kk]);
    }
    int d = (col << 6) + (kk ^ ((col & 7) << 3));
    W1bf[d] = v1;
    W2bf[d] = v2;
  }
  if (idx < 384) {
    int l = idx >> 7, col = idx & 127;
    float v = 0.0f;
    if (col < 120) {
      int sr = srow_of(col);
      v = (l == 0) ? (b_ih0[sr] + b_hh0[sr])
        : (l == 1) ? (b_ih1[sr] + b_hh1[sr])
                   : (b_ih2[sr] + b_hh2[sr]);
    }
    bias[idx] = v;
  }
}

// ---------------- main fused kernel: 64 batch rows / block, 4 waves col-split ----------------
__global__ __launch_bounds__(256, 2) void lstm_main(
    const float* __restrict__ x,
    const unsigned short* __restrict__ W0bf,
    const unsigned short* __restrict__ W1bf,
    const unsigned short* __restrict__ W2bf,
    const float* __restrict__ bias,      // [3][128]
    const float* __restrict__ W_out,     // [4][40]
    const float* __restrict__ b_out,     // [4]
    float* __restrict__ out)
{
  __shared__ __align__(16) unsigned short Abuf[2][64 * 64];    // 16 KB, swizzled bf16 x-tile
  __shared__ __align__(16) unsigned short Wbuf[2][128 * 64];   // 32 KB, chunk image copies
  __shared__ __align__(16) float gates[64 * 124];              // 31.75 KB (cols>=120 never stored)

  const int tid = threadIdx.x;
  const int wave = tid >> 6;
  const int lane = tid & 63;
  const int l15 = lane & 15;
  const int l4 = lane >> 4;
  const long base_row = (long)blockIdx.x * 64;

  const int arow = tid >> 4;  // staging row 0..15 (+p*16)
  const int akq = tid & 15;   // float4 slot
  const float* xbase = x + (base_row + arow) * 1260 + akq * 4;

  f32x4 acc[4][2];
  f32x4 areg[4];
  u32x4 wreg[4];
  const f32x4 zero4 = {0.0f, 0.0f, 0.0f, 0.0f};

  auto zacc = [&]() {
#pragma unroll
    for (int i = 0; i < 4; ++i)
#pragma unroll
      for (int j = 0; j < 2; ++j) acc[i][j] = zero4;
  };

  auto loadA = [&](int c) {
    int kg = (c << 6) + (akq << 2);
    bool v = (kg < 1257);                 // kg+3 < 1260; tail chunk zero-pads
#pragma unroll
    for (int p = 0; p < 4; ++p) {
      const float* s = xbase + p * (16 * 1260) + (c << 6);
      areg[p] = v ? *(const f32x4*)s : zero4;
    }
  };

  auto storeA = [&](int b) {
#pragma unroll
    for (int p = 0; p < 4; ++p) {
      int row = (p << 4) + arow;
      int kk0 = akq << 2;
      int sidx = (row << 6) + (kk0 ^ ((row & 7) << 3));
      u16x4 pk;
      pk.x = f2bf(areg[p].x); pk.y = f2bf(areg[p].y);
      pk.z = f2bf(areg[p].z); pk.w = f2bf(areg[p].w);
      *(u16x4*)&Abuf[b][sidx] = pk;
    }
  };

  auto loadW = [&](const unsigned short* src) {
    const u32x4* ws = (const u32x4*)src;
#pragma unroll
    for (int j = 0; j < 4; ++j) wreg[j] = ws[j * 256 + tid];
  };

  auto storeW = [&](int b) {
    u32x4* wd = (u32x4*)&Wbuf[b][0];
#pragma unroll
    for (int j = 0; j < 4; ++j) wd[j * 256 + tid] = wreg[j];
  };

  auto compute = [&](int b) {
#pragma unroll
    for (int ks = 0; ks < 2; ++ks) {
      bf16x8 af[4], wf[2];
      int kk = (ks << 5) + (l4 << 3);
#pragma unroll
      for (int mt = 0; mt < 4; ++mt) {
        int row = (mt << 4) + l15;
        af[mt] = *(const bf16x8*)&Abuf[b][(row << 6) + (kk ^ ((row & 7) << 3))];
      }
#pragma unroll
      for (int ct = 0; ct < 2; ++ct) {
        int col = (wave << 5) + (ct << 4) + l15;
        wf[ct] = *(const bf16x8*)&Wbuf[b][(col << 6) + (kk ^ ((col & 7) << 3))];
      }
#pragma unroll
      for (int mt = 0; mt < 4; ++mt)
#pragma unroll
        for (int ct = 0; ct < 2; ++ct)
          acc[mt][ct] = __builtin_amdgcn_mfma_f32_16x16x32_bf16(af[mt], wf[ct], acc[mt][ct], 0, 0, 0);
    }
  };

  auto writegates = [&](const float* bp) {
#pragma unroll
    for (int ct = 0; ct < 2; ++ct) {
      int col = (wave << 5) + (ct << 4) + l15;
      if (col < 120) {
        float bv = bp[col];
#pragma unroll
        for (int mt = 0; mt < 4; ++mt) {
          int row = (mt << 4) + (l4 << 2);
#pragma unroll
          for (int r = 0; r < 4; ++r)
            gates[(row + r) * 124 + col] = acc[mt][ct][r] + bv;
        }
      }
    }
  };

  auto zeroA0 = [&]() {
    unsigned int* az = (unsigned int*)&Abuf[0][0];
#pragma unroll
    for (int j = 0; j < 8; ++j) az[j * 256 + tid] = 0u;
  };

  auto act_bf = [&]() {   // gates -> h (bf16) into Abuf[0] A-layout, k=h
#pragma unroll
    for (int it = 0; it < 10; ++it) {
      int idx = it * 256 + tid;
      int row = idx / 40;
      int h = idx - row * 40;
      const float* gr = &gates[row * 124];
      float i = sigm(gr[h]);
      float g = tanh_(gr[40 + h]);
      float o = sigm(gr[80 + h]);
      float hv = o * tanh_(i * g);          // c = i*g (c_prev = 0)
      Abuf[0][(row << 6) + (h ^ ((row & 7) << 3))] = f2bf(hv);
    }
  };

  // ---- layer-0 GEMM over K=1280 (20 chunks), double-buffered ----
  zacc();
  loadA(0); loadW(W0bf);
  storeA(0); storeW(0);
  __syncthreads();
  for (int c = 0; c < 20; ++c) {
    int cur = c & 1;
    if (c < 19) { loadA(c + 1); loadW(W0bf + ((long)(c + 1) << 13)); }
    compute(cur);
    if (c < 19) { storeA(cur ^ 1); storeW(cur ^ 1); }
    __syncthreads();
  }

  // ---- epilogue: activations + layers 1,2 (single-chunk MFMA) + output head ----
  writegates(bias);
  zeroA0();
  loadW(W1bf);
  __syncthreads();

  act_bf();            // h0 -> Abuf[0]
  storeW(0);           // W1 -> Wbuf[0]
  __syncthreads();

  zacc();
  compute(0);          // gates1
  __syncthreads();

  writegates(bias + 128);
  zeroA0();
  loadW(W2bf);
  __syncthreads();

  act_bf();            // h1 -> Abuf[0]
  storeW(0);           // W2 -> Wbuf[0]
  __syncthreads();

  zacc();
  compute(0);          // gates2
  __syncthreads();

  writegates(bias + 256);
  __syncthreads();

  // final activation: h2 (f32) written in-place into gates[row][0..39]
#pragma unroll
  for (int it = 0; it < 10; ++it) {
    int idx = it * 256 + tid;
    int row = idx / 40;
    int h = idx - row * 40;
    float* gr = &gates[row * 124];
    float i = sigm(gr[h]);
    float g = tanh_(gr[40 + h]);
    float o = sigm(gr[80 + h]);
    gr[h] = o * tanh_(i * g);   // safe: only this thread reads/writes [row][h]
  }
  __syncthreads();

  // output head: out[row][oi] = b_out[oi] + sum_h W_out[oi][h] * h2[row][h]
  {
    int row = tid >> 2, oi = tid & 3;
    const float* wo = W_out + oi * 40;
    float s = b_out[oi];
    const float* hr = &gates[row * 124];
#pragma unroll
    for (int h = 0; h < 40; ++h) s = fmaf(wo[h], hr[h], s);
    out[(base_row + row) * 4 + oi] = s;
  }
}

extern "C" void kernel_launch(void* const* d_in, const int* in_sizes, int n_in,
                              void* d_out, int out_size, void* d_ws, size_t ws_size,
                              hipStream_t stream) {
  const float* x     = (const float*)d_in[0];
  const float* W_ih0 = (const float*)d_in[1];
  const float* b_ih0 = (const float*)d_in[3];
  const float* b_hh0 = (const float*)d_in[4];
  const float* W_ih1 = (const float*)d_in[5];
  const float* b_ih1 = (const float*)d_in[7];
  const float* b_hh1 = (const float*)d_in[8];
  const float* W_ih2 = (const float*)d_in[9];
  const float* b_ih2 = (const float*)d_in[11];
  const float* b_hh2 = (const float*)d_in[12];
  const float* W_out = (const float*)d_in[13];
  const float* b_out = (const float*)d_in[14];

  // workspace layout (361,984 B total)
  unsigned short* W0bf = (unsigned short*)d_ws;      // 20*128*64 = 163840 ush
  unsigned short* W1bf = W0bf + 163840;              // 8192 ush
  unsigned short* W2bf = W1bf + 8192;                // 8192 ush
  float* bias = (float*)(W2bf + 8192);               // 384 f32

  if (ws_size < (size_t)(163840 + 8192 + 8192) * 2 + 384 * 4) return;

  prep_kernel<<<640, 256, 0, stream>>>(W_ih0, b_ih0, b_hh0,
                                       W_ih1, b_ih1, b_hh1,
                                       W_ih2, b_ih2, b_hh2,
                                       W0bf, W1bf, W2bf, bias);
  lstm_main<<<1024, 256, 0, stream>>>(x, W0bf, W1bf, W2bf, bias, W_out, b_out, (float*)d_out);
}